// Round 4
// baseline (794.309 us; speedup 1.0000x reference)
//
#include <hip/hip_runtime.h>

// Problem: B=32, C=256, H=W=64, N=4096, R=16.
// out = (w_w @ softmax(x@x^T/16 + w1@w2^T)) @ conv3x3(x_mid, g_w)
// Round 7: revert to round-4 conv structure (weights in LDS, async reg-stage,
// 2 barriers/cib — proven 150us) and widen the wave tile 2x2 -> 2x4 co-frags
// (block co tile 128, grid y=2): LDS reads/MFMA 1.0KB -> 0.75KB, which was
// the round-4 ceiling. Also revert the sim K-split (measured +25us net).

#define NB 32
#define NC 256
#define NPIX 4096   // 64*64

typedef __attribute__((ext_vector_type(8))) short short8;
typedef __attribute__((ext_vector_type(16))) float floatx16;

__device__ inline short f2bf(float f) {
    union { float f; unsigned u; } v; v.f = f;
    unsigned r = v.u + 0x7fffu + ((v.u >> 16) & 1u);   // RNE
    return (short)(r >> 16);
}

// ---------------- random_map = w1 @ w2^T  [256,256] ----------------
__global__ __launch_bounds__(256) void rm_kernel(const float* __restrict__ w1,
                                                 const float* __restrict__ w2,
                                                 float* __restrict__ rm) {
    int idx = blockIdx.x * 256 + threadIdx.x;
    int c = idx >> 8, d = idx & 255;
    float s = 0.f;
#pragma unroll
    for (int r = 0; r < 16; r++) s += w1[c * 16 + r] * w2[d * 16 + r];
    rm[idx] = s;
}

// ---------------- generic fp32 -> bf16 (same layout), 8 elems/thread --------
__global__ __launch_bounds__(256) void cvt_bf16_kernel(const float* __restrict__ in,
                                                       short* __restrict__ out) {
    size_t i = ((size_t)blockIdx.x * 256 + threadIdx.x) * 8;
    float4 v0 = *(const float4*)&in[i];
    float4 v1 = *(const float4*)&in[i + 4];
    short8 s;
    s[0] = f2bf(v0.x); s[1] = f2bf(v0.y); s[2] = f2bf(v0.z); s[3] = f2bf(v0.w);
    s[4] = f2bf(v1.x); s[5] = f2bf(v1.y); s[6] = f2bf(v1.z); s[7] = f2bf(v1.w);
    *(short8*)&out[i] = s;
}

// ---------------- x_mid NCHW fp32 -> xt NHWC bf16 [b][h][w][ci] -------------
__global__ __launch_bounds__(256) void cvt_x_kernel(const float* __restrict__ x,
                                                    short* __restrict__ xt) {
    const int h = blockIdx.x;   // 64
    const int b = blockIdx.y;   // 32
    __shared__ short xls[64 * 256];   // [w][ci]
    const int tid = threadIdx.x;
    for (int i = tid; i < 4096; i += 256) {
        int ci = i >> 4, w4 = (i & 15) << 2;
        float4 v = *(const float4*)&x[(((size_t)(b * 256 + ci)) * 64 + h) * 64 + w4];
        xls[(w4 + 0) * 256 + ci] = f2bf(v.x);
        xls[(w4 + 1) * 256 + ci] = f2bf(v.y);
        xls[(w4 + 2) * 256 + ci] = f2bf(v.z);
        xls[(w4 + 3) * 256 + ci] = f2bf(v.w);
    }
    __syncthreads();
    uint4* dst = (uint4*)&xt[(((size_t)(b * 64 + h)) * 64) * 256];
    const uint4* src = (const uint4*)xls;
    for (int i = tid; i < 2048; i += 256) dst[i] = src[i];
}

// ------ g_w [co][ci][3][3] fp32 -> wt fragment-ordered bf16 -----------------
// wt[co_t(4)][ci_b(16)][tap(9)][ch(2)][ls(64)][j(8)]:
//   co = co_t*64 + ch*32 + (ls&31), ci = ci_b*16 + (ls>>5)*8 + j
__global__ __launch_bounds__(256) void cvt_w_kernel(const float* __restrict__ g_w,
                                                    short* __restrict__ wt) {
    int o = blockIdx.x * 256 + threadIdx.x;   // 73728 total (each = 8 bf16)
    if (o >= 73728) return;
    int co_t = o / 18432;
    int rem  = o - co_t * 18432;
    int ci_b = rem / 1152;
    int rem2 = rem - ci_b * 1152;
    int tap  = rem2 / 128;
    int rem3 = rem2 - tap * 128;
    int ch   = rem3 >> 6, ls = rem3 & 63;
    int co = co_t * 64 + ch * 32 + (ls & 31);
    int ci0 = ci_b * 16 + (ls >> 5) * 8;
    short8 v;
#pragma unroll
    for (int j = 0; j < 8; j++)
        v[j] = f2bf(g_w[((size_t)co * 256 + ci0 + j) * 9 + tap]);
    *(short8*)&wt[(size_t)o * 8] = v;
}

// ---------------- conv3x3 via MFMA -> value_t[b][px][co] bf16 ---------------
// A-operand = x patches (m=px), B-operand = weights (n=co); C[px][co].
// Block tile: 4 h-rows x 128 co. Wave: 64 px x 128 co = 2x4 fragments.
// Async-STAGE: global loads of cib+1 issued into regs before compute of cib;
// LDS writes after the next barrier (round-4 proven structure).
__global__ __launch_bounds__(256) void conv_mfma(const short* __restrict__ xt,
                                                 const short* __restrict__ wt,
                                                 short* __restrict__ value_t) {
    const int h0 = blockIdx.x * 4;
    const int cp = blockIdx.y;           // co0 = cp*128
    const int b  = blockIdx.z;
    __shared__ short ws[2 * 9 * 2 * 64 * 8];   // [cg][tap][ch][ls][8]  36864 B
    __shared__ short xs[6 * 2 * 66 * 8];       // [r][kh2][wx][8]       12672 B
    const int tid = threadIdx.x;
    const int wv = tid >> 6, lane = tid & 63;
    const int kh2 = lane >> 5, ln = lane & 31;

    // ---- per-thread x staging geometry (constant over the K loop) ----
    int xr0, xw0, xh0_, xr1, xw1, xh1_, xr2, xw2, xh2_;
    {
        int i0 = tid;        xr0 = i0 >> 7; int r0 = i0 & 127; xw0 = r0 >> 1; xh0_ = r0 & 1;
        int i1 = tid + 256;  xr1 = i1 >> 7; int r1 = i1 & 127; xw1 = r1 >> 1; xh1_ = r1 & 1;
        int i2 = tid + 512;  xr2 = i2 >> 7; int r2 = i2 & 127; xw2 = r2 >> 1; xh2_ = r2 & 1;
    }
    const int xd0 = (xr0 * 2 + xh0_) * 66 + 1 + xw0;
    const int xd1 = (xr1 * 2 + xh1_) * 66 + 1 + xw1;
    const int xd2 = (xr2 * 2 + xh2_) * 66 + 1 + xw2;
    const int hin0 = h0 - 1 + xr0, hin1 = h0 - 1 + xr1, hin2 = h0 - 1 + xr2;

    // ---- weight staging: 2304 uint4/cib = 9 per thread; src offsets fixed
    // up to +cib*1152. Flat dst i=[cg][tap][ch][ls] matches src slice order.
    const uint4* wbase = (const uint4*)wt;
    uint wsoff[9];
#pragma unroll
    for (int k = 0; k < 9; ++k) {
        int i = tid + 256 * k;
        wsoff[k] = (i < 1152) ? (uint)((cp * 2) * 16 * 1152 + i)
                              : (uint)((cp * 2 + 1) * 16 * 1152 + i - 1152);
    }

    uint4 wr[9];
    uint4 xv0, xv1, xv2;

#define LOAD_CIB(c)                                                            \
    do {                                                                       \
        _Pragma("unroll")                                                      \
        for (int k = 0; k < 9; ++k) wr[k] = wbase[wsoff[k] + (c) * 1152];      \
        xv0 = make_uint4(0, 0, 0, 0); xv1 = xv0; xv2 = xv0;                    \
        if ((unsigned)hin0 < 64u)                                              \
            xv0 = *(const uint4*)&xt[(((size_t)(b * 64 + hin0)) * 64 + xw0) * 256 + (c) * 16 + xh0_ * 8]; \
        if ((unsigned)hin1 < 64u)                                              \
            xv1 = *(const uint4*)&xt[(((size_t)(b * 64 + hin1)) * 64 + xw1) * 256 + (c) * 16 + xh1_ * 8]; \
        if ((unsigned)hin2 < 64u)                                              \
            xv2 = *(const uint4*)&xt[(((size_t)(b * 64 + hin2)) * 64 + xw2) * 256 + (c) * 16 + xh2_ * 8]; \
    } while (0)

#define WRITE_LDS()                                                            \
    do {                                                                       \
        uint4* wdst = (uint4*)ws;                                              \
        _Pragma("unroll")                                                      \
        for (int k = 0; k < 9; ++k) wdst[tid + 256 * k] = wr[k];               \
        uint4* xdst = (uint4*)xs;                                              \
        xdst[xd0] = xv0; xdst[xd1] = xv1; xdst[xd2] = xv2;                     \
    } while (0)

    // halo columns of xs are always zero -> write once, never overwritten
    if (tid < 24) {
        int r = tid >> 2, half = (tid >> 1) & 1, side = tid & 1;
        ((uint4*)xs)[(r * 2 + half) * 66 + side * 65] = make_uint4(0, 0, 0, 0);
    }

    floatx16 acc00 = {}, acc01 = {}, acc02 = {}, acc03 = {};   // px-frag 0
    floatx16 acc10 = {}, acc11 = {}, acc12 = {}, acc13 = {};   // px-frag 1

    LOAD_CIB(0);
    for (int cib = 0; cib < 16; ++cib) {
        __syncthreads();                 // previous compute done reading LDS
        WRITE_LDS();                     // waits vmcnt on staged regs only
        if (cib < 15) LOAD_CIB(cib + 1); // prefetch: in flight across compute
        __syncthreads();                 // LDS writes visible

#pragma unroll
        for (int tap = 0; tap < 9; ++tap) {
            const int kh = tap / 3, kw = tap - kh * 3;
            const int r = wv + kh;
            short8 wf00 = *(const short8*)&ws[(((0 * 9 + tap) * 2 + 0) * 64 + lane) * 8];
            short8 wf01 = *(const short8*)&ws[(((0 * 9 + tap) * 2 + 1) * 64 + lane) * 8];
            short8 wf10 = *(const short8*)&ws[(((1 * 9 + tap) * 2 + 0) * 64 + lane) * 8];
            short8 wf11 = *(const short8*)&ws[(((1 * 9 + tap) * 2 + 1) * 64 + lane) * 8];
            short8 xf0 = *(const short8*)&xs[(((r * 2 + kh2) * 66) + kw + ln) * 8];
            short8 xf1 = *(const short8*)&xs[(((r * 2 + kh2) * 66) + kw + 32 + ln) * 8];
            acc00 = __builtin_amdgcn_mfma_f32_32x32x16_bf16(xf0, wf00, acc00, 0, 0, 0);
            acc01 = __builtin_amdgcn_mfma_f32_32x32x16_bf16(xf0, wf01, acc01, 0, 0, 0);
            acc02 = __builtin_amdgcn_mfma_f32_32x32x16_bf16(xf0, wf10, acc02, 0, 0, 0);
            acc03 = __builtin_amdgcn_mfma_f32_32x32x16_bf16(xf0, wf11, acc03, 0, 0, 0);
            acc10 = __builtin_amdgcn_mfma_f32_32x32x16_bf16(xf1, wf00, acc10, 0, 0, 0);
            acc11 = __builtin_amdgcn_mfma_f32_32x32x16_bf16(xf1, wf01, acc11, 0, 0, 0);
            acc12 = __builtin_amdgcn_mfma_f32_32x32x16_bf16(xf1, wf10, acc12, 0, 0, 0);
            acc13 = __builtin_amdgcn_mfma_f32_32x32x16_bf16(xf1, wf11, acc13, 0, 0, 0);
        }
    }
#undef LOAD_CIB
#undef WRITE_LDS

    // C/D: col(lane&31)=co, row=(reg&3)+8*(reg>>2)+4*kh2 = px within 32-tile
    // co columns: (cg,ch) -> cg*64 + ch*32
    const int h_out = h0 + wv;
    short* vt = value_t + ((size_t)(b * 4096 + h_out * 64)) * 256 + cp * 128;
#pragma unroll
    for (int reg = 0; reg < 16; ++reg) {
        int m = (reg & 3) + 8 * (reg >> 2) + 4 * kh2;
        vt[(size_t)m * 256 + ln]             = f2bf(acc00[reg]);
        vt[(size_t)m * 256 + 32 + ln]        = f2bf(acc01[reg]);
        vt[(size_t)m * 256 + 64 + ln]        = f2bf(acc02[reg]);
        vt[(size_t)m * 256 + 96 + ln]        = f2bf(acc03[reg]);
        vt[(size_t)(m + 32) * 256 + ln]      = f2bf(acc10[reg]);
        vt[(size_t)(m + 32) * 256 + 32 + ln] = f2bf(acc11[reg]);
        vt[(size_t)(m + 32) * 256 + 64 + ln] = f2bf(acc12[reg]);
        vt[(size_t)(m + 32) * 256 + 96 + ln] = f2bf(acc13[reg]);
    }
}

// ------------- bf16 NT-GEMM: C[M,N]fp32 = A[M,K] @ B[N,K]^T -----------------
// Fragments loaded directly from global (both operands K-contiguous).
// Block 128 thr = 2 waves; block tile 64m x 128n; wave: 32m x 4 n-tiles.
__global__ __launch_bounds__(128) void gemm_nt_bf16(const short* __restrict__ A,
                                                    const short* __restrict__ B,
                                                    float* __restrict__ C, int K,
                                                    long sA, long sB, long sC,
                                                    int ldc, int tilesN) {
    const int mt = blockIdx.x / tilesN, nt = blockIdx.x % tilesN;
    A += (size_t)blockIdx.y * sA;
    B += (size_t)blockIdx.y * sB;
    C += (size_t)blockIdx.y * sC;
    const int wv = threadIdx.x >> 6, l = threadIdx.x & 63;
    const int ln = l & 31, kh = l >> 5;
    const short* arow = A + (size_t)(mt * 64 + wv * 32 + ln) * K + kh * 8;
    const short* brow = B + (size_t)(nt * 128 + ln) * K + kh * 8;
    floatx16 acc0 = {}, acc1 = {}, acc2 = {}, acc3 = {};
#pragma unroll 2
    for (int k0 = 0; k0 < K; k0 += 16) {
        short8 a  = *(const short8*)&arow[k0];
        short8 b0 = *(const short8*)&brow[k0];
        short8 b1 = *(const short8*)&brow[(size_t)32 * K + k0];
        short8 b2 = *(const short8*)&brow[(size_t)64 * K + k0];
        short8 b3 = *(const short8*)&brow[(size_t)96 * K + k0];
        acc0 = __builtin_amdgcn_mfma_f32_32x32x16_bf16(a, b0, acc0, 0, 0, 0);
        acc1 = __builtin_amdgcn_mfma_f32_32x32x16_bf16(a, b1, acc1, 0, 0, 0);
        acc2 = __builtin_amdgcn_mfma_f32_32x32x16_bf16(a, b2, acc2, 0, 0, 0);
        acc3 = __builtin_amdgcn_mfma_f32_32x32x16_bf16(a, b3, acc3, 0, 0, 0);
    }
    const int n0 = nt * 128;
#pragma unroll
    for (int reg = 0; reg < 16; ++reg) {
        int m = mt * 64 + wv * 32 + (reg & 3) + 8 * (reg >> 2) + 4 * kh;
        float* crow = C + (size_t)m * ldc + n0 + ln;
        crow[0]  = acc0[reg];
        crow[32] = acc1[reg];
        crow[64] = acc2[reg];
        crow[96] = acc3[reg];
    }
}

// ---------------- fp32 GEMM 64x64 (kept for tiny attn2), opt bf16 out -------
template <int BT, int OB>
__global__ __launch_bounds__(256) void gemm64(const float* __restrict__ A,
                                              const float* __restrict__ B,
                                              float* __restrict__ C, int K,
                                              long sA, long sB, long sC,
                                              int ldA, int ldB, int ldC, int tilesN) {
    const int m0 = (blockIdx.x / tilesN) * 64;
    const int n0 = (blockIdx.x % tilesN) * 64;
    A += (size_t)blockIdx.y * sA;
    B += (size_t)blockIdx.y * sB;
    const size_t coff = (size_t)blockIdx.y * sC;
    __shared__ float As[16][68], Bs[16][68];
    const int tid = threadIdx.x;
    const int tx = tid & 15, ty = tid >> 4;
    const int mm = tid >> 2, kk4 = (tid & 3) * 4;
    float acc[4][4] = {};

    for (int k0 = 0; k0 < K; k0 += 16) {
        __syncthreads();
        {
            float4 a = *(const float4*)&A[(size_t)(m0 + mm) * ldA + k0 + kk4];
            As[kk4 + 0][mm] = a.x; As[kk4 + 1][mm] = a.y;
            As[kk4 + 2][mm] = a.z; As[kk4 + 3][mm] = a.w;
        }
        if (BT) {
            float4 bv = *(const float4*)&B[(size_t)(n0 + mm) * ldB + k0 + kk4];
            Bs[kk4 + 0][mm] = bv.x; Bs[kk4 + 1][mm] = bv.y;
            Bs[kk4 + 2][mm] = bv.z; Bs[kk4 + 3][mm] = bv.w;
        } else {
            int bk = tid >> 4, bn = (tid & 15) * 4;
            *(float4*)&Bs[bk][bn] = *(const float4*)&B[(size_t)(k0 + bk) * ldB + n0 + bn];
        }
        __syncthreads();
#pragma unroll
        for (int kk = 0; kk < 16; kk++) {
            float4 a = *(float4*)&As[kk][ty * 4];
            float4 bv = *(float4*)&Bs[kk][tx * 4];
            float av[4] = {a.x, a.y, a.z, a.w};
            float bb[4] = {bv.x, bv.y, bv.z, bv.w};
#pragma unroll
            for (int i = 0; i < 4; i++)
#pragma unroll
                for (int j = 0; j < 4; j++) acc[i][j] += av[i] * bb[j];
        }
    }
#pragma unroll
    for (int i = 0; i < 4; i++) {
        if (OB) {
            short* Cs = (short*)C + coff;
            short4 o;
            o.x = f2bf(acc[i][0]); o.y = f2bf(acc[i][1]);
            o.z = f2bf(acc[i][2]); o.w = f2bf(acc[i][3]);
            *(short4*)&Cs[(size_t)(m0 + ty * 4 + i) * ldC + n0 + tx * 4] = o;
        } else {
            float* Cf = (float*)C + coff;
            float4 o = make_float4(acc[i][0], acc[i][1], acc[i][2], acc[i][3]);
            *(float4*)&Cf[(size_t)(m0 + ty * 4 + i) * ldC + n0 + tx * 4] = o;
        }
    }
}

// ---------------- softmax over last dim (256) with scale + bias -------------
__global__ __launch_bounds__(256) void softmax_kernel(float* __restrict__ sim,
                                                      const float* __restrict__ rm) {
    int row  = blockIdx.x * 4 + (threadIdx.x >> 6);
    int lane = threadIdx.x & 63;
    int c = row & 255;
    float4 v = *(float4*)&sim[(size_t)row * 256 + lane * 4];
    const float4 bias = *(const float4*)&rm[c * 256 + lane * 4];
    v.x = v.x * 0.0625f + bias.x;
    v.y = v.y * 0.0625f + bias.y;
    v.z = v.z * 0.0625f + bias.z;
    v.w = v.w * 0.0625f + bias.w;
    float m = fmaxf(fmaxf(v.x, v.y), fmaxf(v.z, v.w));
#pragma unroll
    for (int off = 32; off > 0; off >>= 1) m = fmaxf(m, __shfl_xor(m, off, 64));
    float e0 = __expf(v.x - m), e1 = __expf(v.y - m);
    float e2 = __expf(v.z - m), e3 = __expf(v.w - m);
    float s = e0 + e1 + e2 + e3;
#pragma unroll
    for (int off = 32; off > 0; off >>= 1) s += __shfl_xor(s, off, 64);
    float inv = 1.f / s;
    float4 o = make_float4(e0 * inv, e1 * inv, e2 * inv, e3 * inv);
    *(float4*)&sim[(size_t)row * 256 + lane * 4] = o;
}

extern "C" void kernel_launch(void* const* d_in, const int* in_sizes, int n_in,
                              void* d_out, int out_size, void* d_ws, size_t ws_size,
                              hipStream_t stream) {
    const float* x     = (const float*)d_in[0];
    const float* x_mid = (const float*)d_in[1];
    const float* g_w   = (const float*)d_in[2];
    const float* w_w   = (const float*)d_in[3];
    const float* w1    = (const float*)d_in[4];
    const float* w2    = (const float*)d_in[5];
    float* out = (float*)d_out;

    char* ws = (char*)d_ws;
    short* value_t = (short*)ws;                                   // 67.1 MB [b][px][co]
    float* sim     = (float*)(ws + (size_t)NB * NPIX * NC * 2);    // 8.4 MB
    short* attn2_b = (short*)(sim + (size_t)NB * NC * NC);         // 4.2 MB [b][co][d]
    float* rm      = (float*)(attn2_b + (size_t)NB * NC * NC);     // 0.26 MB
    short* xt      = (short*)(rm + NC * NC);                       // 67.1 MB
    short* xb      = xt + (size_t)NB * NPIX * NC;                  // 67.1 MB
    short* wt      = xb + (size_t)NB * NC * NPIX;                  // 1.18 MB

    cvt_w_kernel<<<288, 256, 0, stream>>>(g_w, wt);
    cvt_x_kernel<<<dim3(64, 32), 256, 0, stream>>>(x_mid, xt);
    cvt_bf16_kernel<<<16384, 256, 0, stream>>>(x, xb);
    rm_kernel<<<256, 256, 0, stream>>>(w1, w2, rm);
    // value_t[b][px][co] = conv3x3(x_mid, g_w)
    conv_mfma<<<dim3(16, 2, 32), 256, 0, stream>>>(xt, wt, value_t);
    // sim = xb @ xb^T   (M=N=256, K=4096)
    gemm_nt_bf16<<<dim3(8, 32), 128, 0, stream>>>(
        xb, xb, sim, 4096,
        (long)NC * NPIX, (long)NC * NPIX, (long)NC * NC, NC, 2);
    softmax_kernel<<<2048, 256, 0, stream>>>(sim, rm);
    // attn2_b = bf16(w_w @ attn)  (M=N=K=256; A not batched)
    gemm64<0, 1><<<dim3(16, 32), 256, 0, stream>>>(
        w_w, sim, (float*)attn2_b, 256,
        0L, (long)NC * NC, (long)NC * NC,
        NC, NC, NC, 4);
    // out[b][co][px] = attn2_b @ value_t^T  (M=256, N=4096, K=256)
    gemm_nt_bf16<<<dim3(128, 32), 128, 0, stream>>>(
        attn2_b, value_t, out, 256,
        (long)NC * NC, (long)NPIX * NC, (long)NC * NPIX, NPIX, 32);
}

// Round 5
// 684.421 us; speedup vs baseline: 1.1606x; 1.1606x over previous
//
#include <hip/hip_runtime.h>

// Problem: B=32, C=256, H=W=64, N=4096, R=16.
// out = (w_w @ softmax(x@x^T/16 + w1@w2^T)) @ conv3x3(x_mid, g_w)
// Round 8: conv = round-4 structure (2x2 wave tile, async x reg-stage,
// 2 barriers/cib) but weights staged via global_load_lds into double-buffered
// ws: frees 20 staging VGPRs (-> 3 waves/SIMD), kills weight ds_writes, LDS
// 49.5KB -> 3 blocks/CU. STAGE_W issued right after barrier B so its vmcnt
// drain lands at the NEXT barrier A (after the full compute phase). No K-split.

#define NB 32
#define NC 256
#define NPIX 4096   // 64*64

typedef __attribute__((ext_vector_type(8))) short short8;
typedef __attribute__((ext_vector_type(16))) float floatx16;

typedef __attribute__((address_space(1))) const unsigned int guint;
typedef __attribute__((address_space(3))) unsigned int luint;

__device__ inline short f2bf(float f) {
    union { float f; unsigned u; } v; v.f = f;
    unsigned r = v.u + 0x7fffu + ((v.u >> 16) & 1u);   // RNE
    return (short)(r >> 16);
}

// ---------------- random_map = w1 @ w2^T  [256,256] ----------------
__global__ __launch_bounds__(256) void rm_kernel(const float* __restrict__ w1,
                                                 const float* __restrict__ w2,
                                                 float* __restrict__ rm) {
    int idx = blockIdx.x * 256 + threadIdx.x;
    int c = idx >> 8, d = idx & 255;
    float s = 0.f;
#pragma unroll
    for (int r = 0; r < 16; r++) s += w1[c * 16 + r] * w2[d * 16 + r];
    rm[idx] = s;
}

// ---------------- generic fp32 -> bf16 (same layout), 8 elems/thread --------
__global__ __launch_bounds__(256) void cvt_bf16_kernel(const float* __restrict__ in,
                                                       short* __restrict__ out) {
    size_t i = ((size_t)blockIdx.x * 256 + threadIdx.x) * 8;
    float4 v0 = *(const float4*)&in[i];
    float4 v1 = *(const float4*)&in[i + 4];
    short8 s;
    s[0] = f2bf(v0.x); s[1] = f2bf(v0.y); s[2] = f2bf(v0.z); s[3] = f2bf(v0.w);
    s[4] = f2bf(v1.x); s[5] = f2bf(v1.y); s[6] = f2bf(v1.z); s[7] = f2bf(v1.w);
    *(short8*)&out[i] = s;
}

// ---------------- x_mid NCHW fp32 -> xt NHWC bf16 [b][h][w][ci] -------------
__global__ __launch_bounds__(256) void cvt_x_kernel(const float* __restrict__ x,
                                                    short* __restrict__ xt) {
    const int h = blockIdx.x;   // 64
    const int b = blockIdx.y;   // 32
    __shared__ short xls[64 * 256];   // [w][ci]
    const int tid = threadIdx.x;
    for (int i = tid; i < 4096; i += 256) {
        int ci = i >> 4, w4 = (i & 15) << 2;
        float4 v = *(const float4*)&x[(((size_t)(b * 256 + ci)) * 64 + h) * 64 + w4];
        xls[(w4 + 0) * 256 + ci] = f2bf(v.x);
        xls[(w4 + 1) * 256 + ci] = f2bf(v.y);
        xls[(w4 + 2) * 256 + ci] = f2bf(v.z);
        xls[(w4 + 3) * 256 + ci] = f2bf(v.w);
    }
    __syncthreads();
    uint4* dst = (uint4*)&xt[(((size_t)(b * 64 + h)) * 64) * 256];
    const uint4* src = (const uint4*)xls;
    for (int i = tid; i < 2048; i += 256) dst[i] = src[i];
}

// ------ g_w [co][ci][3][3] fp32 -> wt fragment-ordered bf16 -----------------
// wt[co_t(4)][ci_b(16)][tap(9)][ch(2)][ls(64)][j(8)]:
//   co = co_t*64 + ch*32 + (ls&31), ci = ci_b*16 + (ls>>5)*8 + j
__global__ __launch_bounds__(256) void cvt_w_kernel(const float* __restrict__ g_w,
                                                    short* __restrict__ wt) {
    int o = blockIdx.x * 256 + threadIdx.x;   // 73728 total (each = 8 bf16)
    if (o >= 73728) return;
    int co_t = o / 18432;
    int rem  = o - co_t * 18432;
    int ci_b = rem / 1152;
    int rem2 = rem - ci_b * 1152;
    int tap  = rem2 / 128;
    int rem3 = rem2 - tap * 128;
    int ch   = rem3 >> 6, ls = rem3 & 63;
    int co = co_t * 64 + ch * 32 + (ls & 31);
    int ci0 = ci_b * 16 + (ls >> 5) * 8;
    short8 v;
#pragma unroll
    for (int j = 0; j < 8; j++)
        v[j] = f2bf(g_w[((size_t)co * 256 + ci0 + j) * 9 + tap]);
    *(short8*)&wt[(size_t)o * 8] = v;
}

// ---------------- conv3x3 via MFMA -> value_t[b][px][co] bf16 ---------------
// A-operand = x patches (m=px), B-operand = weights (n=co); C[px][co].
// x: async reg-stage into single xs buffer (2 barriers/cib, round-4 proven).
// w: global_load_lds into double-buffered ws; issued at compute start so the
//    vmcnt(0) drain (compiler-emitted before s_barrier) lands after compute.
__global__ __launch_bounds__(256) void conv_mfma(const short* __restrict__ xt,
                                                 const short* __restrict__ wt,
                                                 short* __restrict__ value_t) {
    const int h0  = blockIdx.x * 4;
    const int cot = blockIdx.y;          // co0 = cot*64
    const int b   = blockIdx.z;
    __shared__ short ws[2][9 * 2 * 64 * 8];  // dbuf [tap][ch][ls][8] 18432 B each
    __shared__ short xs[6 * 2 * 66 * 8];     // [r][kh2][wx][8]      12672 B
    const int tid = threadIdx.x;
    const int wv = tid >> 6, lane = tid & 63;
    const int kh2 = lane >> 5, ln = lane & 31;

    // ---- per-thread x staging geometry (constant over the K loop) ----
    int xr0, xw0, xh0_, xr1, xw1, xh1_, xr2, xw2, xh2_;
    {
        int i0 = tid;        xr0 = i0 >> 7; int r0 = i0 & 127; xw0 = r0 >> 1; xh0_ = r0 & 1;
        int i1 = tid + 256;  xr1 = i1 >> 7; int r1 = i1 & 127; xw1 = r1 >> 1; xh1_ = r1 & 1;
        int i2 = tid + 512;  xr2 = i2 >> 7; int r2 = i2 & 127; xw2 = r2 >> 1; xh2_ = r2 & 1;
    }
    const int xd0 = (xr0 * 2 + xh0_) * 66 + 1 + xw0;
    const int xd1 = (xr1 * 2 + xh1_) * 66 + 1 + xw1;
    const int xd2 = (xr2 * 2 + xh2_) * 66 + 1 + xw2;
    const int hin0 = h0 - 1 + xr0, hin1 = h0 - 1 + xr1, hin2 = h0 - 1 + xr2;

    const short* wsrc0 = wt + (size_t)(cot * 16) * 1152 * 8;

    // Stage weights for ci-block c into ws[c&1]: 18 chunks of 1024B, spread
    // over 4 waves; dst = wave-uniform base + lane*16 (gload_lds layout).
#define STAGE_W(c)                                                             \
    do {                                                                       \
        short* wsd = ws[(c) & 1];                                              \
        const short* wsg = wsrc0 + (size_t)(c) * 1152 * 8;                     \
        _Pragma("unroll")                                                      \
        for (int j = 0; j < 5; ++j) {                                          \
            int k = wv + 4 * j;                                                \
            if (k < 18)                                                        \
                __builtin_amdgcn_global_load_lds(                              \
                    (guint*)(wsg + (size_t)(k * 64 + lane) * 8),               \
                    (luint*)(wsd + k * 512), 16, 0, 0);                        \
        }                                                                      \
    } while (0)

    uint4 xv0, xv1, xv2;
#define LOAD_X(c)                                                              \
    do {                                                                       \
        xv0 = make_uint4(0, 0, 0, 0); xv1 = xv0; xv2 = xv0;                    \
        if ((unsigned)hin0 < 64u)                                              \
            xv0 = *(const uint4*)&xt[(((size_t)(b * 64 + hin0)) * 64 + xw0) * 256 + (c) * 16 + xh0_ * 8]; \
        if ((unsigned)hin1 < 64u)                                              \
            xv1 = *(const uint4*)&xt[(((size_t)(b * 64 + hin1)) * 64 + xw1) * 256 + (c) * 16 + xh1_ * 8]; \
        if ((unsigned)hin2 < 64u)                                              \
            xv2 = *(const uint4*)&xt[(((size_t)(b * 64 + hin2)) * 64 + xw2) * 256 + (c) * 16 + xh2_ * 8]; \
    } while (0)

    // halo columns of xs are always zero -> write once, never overwritten
    if (tid < 24) {
        int r = tid >> 2, half = (tid >> 1) & 1, side = tid & 1;
        ((uint4*)xs)[(r * 2 + half) * 66 + side * 65] = make_uint4(0, 0, 0, 0);
    }

    floatx16 acc00 = {}, acc01 = {}, acc10 = {}, acc11 = {};   // [pxh][coh]

    STAGE_W(0);
    LOAD_X(0);
    for (int cib = 0; cib < 16; ++cib) {
        __syncthreads();   // A: prev compute done; drains STAGE_W(cib)+LOAD_X(cib)
        {   // write staged x regs into xs
            uint4* xdst = (uint4*)xs;
            xdst[xd0] = xv0; xdst[xd1] = xv1; xdst[xd2] = xv2;
        }
        __syncthreads();   // B: xs writes visible (no outstanding gload_lds here)
        if (cib < 15) {
            STAGE_W(cib + 1);   // in flight across the whole compute phase
            LOAD_X(cib + 1);    // reg loads survive barriers
        }

        const short* wsc = ws[cib & 1];
#pragma unroll
        for (int tap = 0; tap < 9; ++tap) {
            const int kh = tap / 3, kw = tap - kh * 3;
            const int r = wv + kh;
            short8 wf0 = *(const short8*)&wsc[((tap * 2 + 0) * 64 + lane) * 8];
            short8 wf1 = *(const short8*)&wsc[((tap * 2 + 1) * 64 + lane) * 8];
            short8 xf0 = *(const short8*)&xs[(((r * 2 + kh2) * 66) + kw + ln) * 8];
            short8 xf1 = *(const short8*)&xs[(((r * 2 + kh2) * 66) + kw + 32 + ln) * 8];
            acc00 = __builtin_amdgcn_mfma_f32_32x32x16_bf16(xf0, wf0, acc00, 0, 0, 0);
            acc01 = __builtin_amdgcn_mfma_f32_32x32x16_bf16(xf0, wf1, acc01, 0, 0, 0);
            acc10 = __builtin_amdgcn_mfma_f32_32x32x16_bf16(xf1, wf0, acc10, 0, 0, 0);
            acc11 = __builtin_amdgcn_mfma_f32_32x32x16_bf16(xf1, wf1, acc11, 0, 0, 0);
        }
    }
#undef LOAD_X
#undef STAGE_W

    // C/D: col(lane&31)=co, row=(reg&3)+8*(reg>>2)+4*kh2 = px within 32-tile
    const int h_out = h0 + wv;
    short* vt = value_t + ((size_t)(b * 4096 + h_out * 64)) * 256 + cot * 64;
#pragma unroll
    for (int reg = 0; reg < 16; ++reg) {
        int m = (reg & 3) + 8 * (reg >> 2) + 4 * kh2;
        vt[(size_t)m * 256 + ln]             = f2bf(acc00[reg]);
        vt[(size_t)m * 256 + 32 + ln]        = f2bf(acc01[reg]);
        vt[(size_t)(m + 32) * 256 + ln]      = f2bf(acc10[reg]);
        vt[(size_t)(m + 32) * 256 + 32 + ln] = f2bf(acc11[reg]);
    }
}

// ------------- bf16 NT-GEMM: C[M,N]fp32 = A[M,K] @ B[N,K]^T -----------------
// Fragments loaded directly from global (both operands K-contiguous).
// Block 128 thr = 2 waves; block tile 64m x 128n; wave: 32m x 4 n-tiles.
__global__ __launch_bounds__(128) void gemm_nt_bf16(const short* __restrict__ A,
                                                    const short* __restrict__ B,
                                                    float* __restrict__ C, int K,
                                                    long sA, long sB, long sC,
                                                    int ldc, int tilesN) {
    const int mt = blockIdx.x / tilesN, nt = blockIdx.x % tilesN;
    A += (size_t)blockIdx.y * sA;
    B += (size_t)blockIdx.y * sB;
    C += (size_t)blockIdx.y * sC;
    const int wv = threadIdx.x >> 6, l = threadIdx.x & 63;
    const int ln = l & 31, kh = l >> 5;
    const short* arow = A + (size_t)(mt * 64 + wv * 32 + ln) * K + kh * 8;
    const short* brow = B + (size_t)(nt * 128 + ln) * K + kh * 8;
    floatx16 acc0 = {}, acc1 = {}, acc2 = {}, acc3 = {};
#pragma unroll 2
    for (int k0 = 0; k0 < K; k0 += 16) {
        short8 a  = *(const short8*)&arow[k0];
        short8 b0 = *(const short8*)&brow[k0];
        short8 b1 = *(const short8*)&brow[(size_t)32 * K + k0];
        short8 b2 = *(const short8*)&brow[(size_t)64 * K + k0];
        short8 b3 = *(const short8*)&brow[(size_t)96 * K + k0];
        acc0 = __builtin_amdgcn_mfma_f32_32x32x16_bf16(a, b0, acc0, 0, 0, 0);
        acc1 = __builtin_amdgcn_mfma_f32_32x32x16_bf16(a, b1, acc1, 0, 0, 0);
        acc2 = __builtin_amdgcn_mfma_f32_32x32x16_bf16(a, b2, acc2, 0, 0, 0);
        acc3 = __builtin_amdgcn_mfma_f32_32x32x16_bf16(a, b3, acc3, 0, 0, 0);
    }
    const int n0 = nt * 128;
#pragma unroll
    for (int reg = 0; reg < 16; ++reg) {
        int m = mt * 64 + wv * 32 + (reg & 3) + 8 * (reg >> 2) + 4 * kh;
        float* crow = C + (size_t)m * ldc + n0 + ln;
        crow[0]  = acc0[reg];
        crow[32] = acc1[reg];
        crow[64] = acc2[reg];
        crow[96] = acc3[reg];
    }
}

// ---------------- fp32 GEMM 64x64 (kept for tiny attn2), opt bf16 out -------
template <int BT, int OB>
__global__ __launch_bounds__(256) void gemm64(const float* __restrict__ A,
                                              const float* __restrict__ B,
                                              float* __restrict__ C, int K,
                                              long sA, long sB, long sC,
                                              int ldA, int ldB, int ldC, int tilesN) {
    const int m0 = (blockIdx.x / tilesN) * 64;
    const int n0 = (blockIdx.x % tilesN) * 64;
    A += (size_t)blockIdx.y * sA;
    B += (size_t)blockIdx.y * sB;
    const size_t coff = (size_t)blockIdx.y * sC;
    __shared__ float As[16][68], Bs[16][68];
    const int tid = threadIdx.x;
    const int tx = tid & 15, ty = tid >> 4;
    const int mm = tid >> 2, kk4 = (tid & 3) * 4;
    float acc[4][4] = {};

    for (int k0 = 0; k0 < K; k0 += 16) {
        __syncthreads();
        {
            float4 a = *(const float4*)&A[(size_t)(m0 + mm) * ldA + k0 + kk4];
            As[kk4 + 0][mm] = a.x; As[kk4 + 1][mm] = a.y;
            As[kk4 + 2][mm] = a.z; As[kk4 + 3][mm] = a.w;
        }
        if (BT) {
            float4 bv = *(const float4*)&B[(size_t)(n0 + mm) * ldB + k0 + kk4];
            Bs[kk4 + 0][mm] = bv.x; Bs[kk4 + 1][mm] = bv.y;
            Bs[kk4 + 2][mm] = bv.z; Bs[kk4 + 3][mm] = bv.w;
        } else {
            int bk = tid >> 4, bn = (tid & 15) * 4;
            *(float4*)&Bs[bk][bn] = *(const float4*)&B[(size_t)(k0 + bk) * ldB + n0 + bn];
        }
        __syncthreads();
#pragma unroll
        for (int kk = 0; kk < 16; kk++) {
            float4 a = *(float4*)&As[kk][ty * 4];
            float4 bv = *(float4*)&Bs[kk][tx * 4];
            float av[4] = {a.x, a.y, a.z, a.w};
            float bb[4] = {bv.x, bv.y, bv.z, bv.w};
#pragma unroll
            for (int i = 0; i < 4; i++)
#pragma unroll
                for (int j = 0; j < 4; j++) acc[i][j] += av[i] * bb[j];
        }
    }
#pragma unroll
    for (int i = 0; i < 4; i++) {
        if (OB) {
            short* Cs = (short*)C + coff;
            short4 o;
            o.x = f2bf(acc[i][0]); o.y = f2bf(acc[i][1]);
            o.z = f2bf(acc[i][2]); o.w = f2bf(acc[i][3]);
            *(short4*)&Cs[(size_t)(m0 + ty * 4 + i) * ldC + n0 + tx * 4] = o;
        } else {
            float* Cf = (float*)C + coff;
            float4 o = make_float4(acc[i][0], acc[i][1], acc[i][2], acc[i][3]);
            *(float4*)&Cf[(size_t)(m0 + ty * 4 + i) * ldC + n0 + tx * 4] = o;
        }
    }
}

// ---------------- softmax over last dim (256) with scale + bias -------------
__global__ __launch_bounds__(256) void softmax_kernel(float* __restrict__ sim,
                                                      const float* __restrict__ rm) {
    int row  = blockIdx.x * 4 + (threadIdx.x >> 6);
    int lane = threadIdx.x & 63;
    int c = row & 255;
    float4 v = *(float4*)&sim[(size_t)row * 256 + lane * 4];
    const float4 bias = *(const float4*)&rm[c * 256 + lane * 4];
    v.x = v.x * 0.0625f + bias.x;
    v.y = v.y * 0.0625f + bias.y;
    v.z = v.z * 0.0625f + bias.z;
    v.w = v.w * 0.0625f + bias.w;
    float m = fmaxf(fmaxf(v.x, v.y), fmaxf(v.z, v.w));
#pragma unroll
    for (int off = 32; off > 0; off >>= 1) m = fmaxf(m, __shfl_xor(m, off, 64));
    float e0 = __expf(v.x - m), e1 = __expf(v.y - m);
    float e2 = __expf(v.z - m), e3 = __expf(v.w - m);
    float s = e0 + e1 + e2 + e3;
#pragma unroll
    for (int off = 32; off > 0; off >>= 1) s += __shfl_xor(s, off, 64);
    float inv = 1.f / s;
    float4 o = make_float4(e0 * inv, e1 * inv, e2 * inv, e3 * inv);
    *(float4*)&sim[(size_t)row * 256 + lane * 4] = o;
}

extern "C" void kernel_launch(void* const* d_in, const int* in_sizes, int n_in,
                              void* d_out, int out_size, void* d_ws, size_t ws_size,
                              hipStream_t stream) {
    const float* x     = (const float*)d_in[0];
    const float* x_mid = (const float*)d_in[1];
    const float* g_w   = (const float*)d_in[2];
    const float* w_w   = (const float*)d_in[3];
    const float* w1    = (const float*)d_in[4];
    const float* w2    = (const float*)d_in[5];
    float* out = (float*)d_out;

    char* ws = (char*)d_ws;
    short* value_t = (short*)ws;                                   // 67.1 MB [b][px][co]
    float* sim     = (float*)(ws + (size_t)NB * NPIX * NC * 2);    // 8.4 MB
    short* attn2_b = (short*)(sim + (size_t)NB * NC * NC);         // 4.2 MB [b][co][d]
    float* rm      = (float*)(attn2_b + (size_t)NB * NC * NC);     // 0.26 MB
    short* xt      = (short*)(rm + NC * NC);                       // 67.1 MB
    short* xb      = xt + (size_t)NB * NPIX * NC;                  // 67.1 MB
    short* wt      = xb + (size_t)NB * NC * NPIX;                  // 1.18 MB

    cvt_w_kernel<<<288, 256, 0, stream>>>(g_w, wt);
    cvt_x_kernel<<<dim3(64, 32), 256, 0, stream>>>(x_mid, xt);
    cvt_bf16_kernel<<<16384, 256, 0, stream>>>(x, xb);
    rm_kernel<<<256, 256, 0, stream>>>(w1, w2, rm);
    // value_t[b][px][co] = conv3x3(x_mid, g_w)
    conv_mfma<<<dim3(16, 4, 32), 256, 0, stream>>>(xt, wt, value_t);
    // sim = xb @ xb^T   (M=N=256, K=4096)
    gemm_nt_bf16<<<dim3(8, 32), 128, 0, stream>>>(
        xb, xb, sim, 4096,
        (long)NC * NPIX, (long)NC * NPIX, (long)NC * NC, NC, 2);
    softmax_kernel<<<2048, 256, 0, stream>>>(sim, rm);
    // attn2_b = bf16(w_w @ attn)  (M=N=K=256; A not batched)
    gemm64<0, 1><<<dim3(16, 32), 256, 0, stream>>>(
        w_w, sim, (float*)attn2_b, 256,
        0L, (long)NC * NC, (long)NC * NC,
        NC, NC, NC, 4);
    // out[b][co][px] = attn2_b @ value_t^T  (M=256, N=4096, K=256)
    gemm_nt_bf16<<<dim3(128, 32), 128, 0, stream>>>(
        attn2_b, value_t, out, 256,
        (long)NC * NC, (long)NPIX * NC, (long)NC * NPIX, NPIX, 32);
}

// Round 6
// 676.876 us; speedup vs baseline: 1.1735x; 1.0111x over previous
//
#include <hip/hip_runtime.h>

// Problem: B=32, C=256, H=W=64, N=4096, R=16.
// out = (w_w @ softmax(x@x^T/16 + w1@w2^T)) @ conv3x3(x_mid, g_w)
// Round 9: conv reverted to the measured-best round-4 structure (reg-staged
// weights+x, single LDS buffers, 2 barriers/cib, 4 blocks/CU resident).
// Final GEMM retiled to 512-thr blocks, tile 256m x 128n: all 8 waves share
// the same B rows (L1 broadcast) -> value_t read ONCE from HBM (268->67MB).

#define NB 32
#define NC 256
#define NPIX 4096   // 64*64

typedef __attribute__((ext_vector_type(8))) short short8;
typedef __attribute__((ext_vector_type(16))) float floatx16;

__device__ inline short f2bf(float f) {
    union { float f; unsigned u; } v; v.f = f;
    unsigned r = v.u + 0x7fffu + ((v.u >> 16) & 1u);   // RNE
    return (short)(r >> 16);
}

// ---------------- random_map = w1 @ w2^T  [256,256] ----------------
__global__ __launch_bounds__(256) void rm_kernel(const float* __restrict__ w1,
                                                 const float* __restrict__ w2,
                                                 float* __restrict__ rm) {
    int idx = blockIdx.x * 256 + threadIdx.x;
    int c = idx >> 8, d = idx & 255;
    float s = 0.f;
#pragma unroll
    for (int r = 0; r < 16; r++) s += w1[c * 16 + r] * w2[d * 16 + r];
    rm[idx] = s;
}

// ---------------- generic fp32 -> bf16 (same layout), 8 elems/thread --------
__global__ __launch_bounds__(256) void cvt_bf16_kernel(const float* __restrict__ in,
                                                       short* __restrict__ out) {
    size_t i = ((size_t)blockIdx.x * 256 + threadIdx.x) * 8;
    float4 v0 = *(const float4*)&in[i];
    float4 v1 = *(const float4*)&in[i + 4];
    short8 s;
    s[0] = f2bf(v0.x); s[1] = f2bf(v0.y); s[2] = f2bf(v0.z); s[3] = f2bf(v0.w);
    s[4] = f2bf(v1.x); s[5] = f2bf(v1.y); s[6] = f2bf(v1.z); s[7] = f2bf(v1.w);
    *(short8*)&out[i] = s;
}

// ---------------- x_mid NCHW fp32 -> xt NHWC bf16 [b][h][w][ci] -------------
__global__ __launch_bounds__(256) void cvt_x_kernel(const float* __restrict__ x,
                                                    short* __restrict__ xt) {
    const int h = blockIdx.x;   // 64
    const int b = blockIdx.y;   // 32
    __shared__ short xls[64 * 256];   // [w][ci]
    const int tid = threadIdx.x;
    for (int i = tid; i < 4096; i += 256) {
        int ci = i >> 4, w4 = (i & 15) << 2;
        float4 v = *(const float4*)&x[(((size_t)(b * 256 + ci)) * 64 + h) * 64 + w4];
        xls[(w4 + 0) * 256 + ci] = f2bf(v.x);
        xls[(w4 + 1) * 256 + ci] = f2bf(v.y);
        xls[(w4 + 2) * 256 + ci] = f2bf(v.z);
        xls[(w4 + 3) * 256 + ci] = f2bf(v.w);
    }
    __syncthreads();
    uint4* dst = (uint4*)&xt[(((size_t)(b * 64 + h)) * 64) * 256];
    const uint4* src = (const uint4*)xls;
    for (int i = tid; i < 2048; i += 256) dst[i] = src[i];
}

// ------ g_w [co][ci][3][3] fp32 -> wt fragment-ordered bf16 -----------------
// wt[co_t(4)][ci_b(16)][tap(9)][ch(2)][ls(64)][j(8)]:
//   co = co_t*64 + ch*32 + (ls&31), ci = ci_b*16 + (ls>>5)*8 + j
__global__ __launch_bounds__(256) void cvt_w_kernel(const float* __restrict__ g_w,
                                                    short* __restrict__ wt) {
    int o = blockIdx.x * 256 + threadIdx.x;   // 73728 total (each = 8 bf16)
    if (o >= 73728) return;
    int co_t = o / 18432;
    int rem  = o - co_t * 18432;
    int ci_b = rem / 1152;
    int rem2 = rem - ci_b * 1152;
    int tap  = rem2 / 128;
    int rem3 = rem2 - tap * 128;
    int ch   = rem3 >> 6, ls = rem3 & 63;
    int co = co_t * 64 + ch * 32 + (ls & 31);
    int ci0 = ci_b * 16 + (ls >> 5) * 8;
    short8 v;
#pragma unroll
    for (int j = 0; j < 8; j++)
        v[j] = f2bf(g_w[((size_t)co * 256 + ci0 + j) * 9 + tap]);
    *(short8*)&wt[(size_t)o * 8] = v;
}

// ---------------- conv3x3 via MFMA -> value_t[b][px][co] bf16 ---------------
// A-operand = x patches (m=px), B-operand = weights (n=co); C[px][co].
// Round-4 proven structure: async reg-stage of cib+1 issued before compute of
// cib, LDS writes between the two barriers. 4 blocks/CU resident.
__global__ __launch_bounds__(256) void conv_mfma(const short* __restrict__ xt,
                                                 const short* __restrict__ wt,
                                                 short* __restrict__ value_t) {
    const int h0  = blockIdx.x * 4;
    const int cot = blockIdx.y;          // co0 = cot*64
    const int b   = blockIdx.z;
    __shared__ short ws[9 * 2 * 64 * 8];     // [tap][ch][ls][8]  18432 B
    __shared__ short xs[6 * 2 * 66 * 8];     // [r][kh2][wx][8]   12672 B
    const int tid = threadIdx.x;
    const int wv = tid >> 6, lane = tid & 63;
    const int kh2 = lane >> 5, ln = lane & 31;

    // ---- per-thread staging geometry (constant over the K loop) ----
    int xr0, xw0, xh0_, xr1, xw1, xh1_, xr2, xw2, xh2_;
    {
        int i0 = tid;        xr0 = i0 >> 7; int r0 = i0 & 127; xw0 = r0 >> 1; xh0_ = r0 & 1;
        int i1 = tid + 256;  xr1 = i1 >> 7; int r1 = i1 & 127; xw1 = r1 >> 1; xh1_ = r1 & 1;
        int i2 = tid + 512;  xr2 = i2 >> 7; int r2 = i2 & 127; xw2 = r2 >> 1; xh2_ = r2 & 1;
    }
    const int xd0 = (xr0 * 2 + xh0_) * 66 + 1 + xw0;
    const int xd1 = (xr1 * 2 + xh1_) * 66 + 1 + xw1;
    const int xd2 = (xr2 * 2 + xh2_) * 66 + 1 + xw2;
    const int hin0 = h0 - 1 + xr0, hin1 = h0 - 1 + xr1, hin2 = h0 - 1 + xr2;
    const uint4* wsrc_base = (const uint4*)&wt[(size_t)(cot * 16) * 1152 * 8];

    uint4 wr0, wr1, wr2, wr3, wr4;
    uint4 xv0, xv1, xv2;

#define LOAD_CIB(c)                                                            \
    do {                                                                       \
        const uint4* wsrc = wsrc_base + (size_t)(c) * 1152;                    \
        wr0 = wsrc[tid];        wr1 = wsrc[tid + 256];                         \
        wr2 = wsrc[tid + 512];  wr3 = wsrc[tid + 768];                         \
        if (tid < 128) wr4 = wsrc[tid + 1024];                                 \
        xv0 = make_uint4(0, 0, 0, 0); xv1 = xv0; xv2 = xv0;                    \
        if ((unsigned)hin0 < 64u)                                              \
            xv0 = *(const uint4*)&xt[(((size_t)(b * 64 + hin0)) * 64 + xw0) * 256 + (c) * 16 + xh0_ * 8]; \
        if ((unsigned)hin1 < 64u)                                              \
            xv1 = *(const uint4*)&xt[(((size_t)(b * 64 + hin1)) * 64 + xw1) * 256 + (c) * 16 + xh1_ * 8]; \
        if ((unsigned)hin2 < 64u)                                              \
            xv2 = *(const uint4*)&xt[(((size_t)(b * 64 + hin2)) * 64 + xw2) * 256 + (c) * 16 + xh2_ * 8]; \
    } while (0)

#define WRITE_LDS()                                                            \
    do {                                                                       \
        uint4* wdst = (uint4*)ws;                                              \
        wdst[tid] = wr0;        wdst[tid + 256] = wr1;                         \
        wdst[tid + 512] = wr2;  wdst[tid + 768] = wr3;                         \
        if (tid < 128) wdst[tid + 1024] = wr4;                                 \
        uint4* xdst = (uint4*)xs;                                              \
        xdst[xd0] = xv0; xdst[xd1] = xv1; xdst[xd2] = xv2;                     \
    } while (0)

    // halo columns of xs are always zero -> write once, never overwritten
    if (tid < 24) {
        int r = tid >> 2, half = (tid >> 1) & 1, side = tid & 1;
        ((uint4*)xs)[(r * 2 + half) * 66 + side * 65] = make_uint4(0, 0, 0, 0);
    }

    floatx16 acc00 = {}, acc01 = {}, acc10 = {}, acc11 = {};   // [pxh][coh]

    LOAD_CIB(0);
    for (int cib = 0; cib < 16; ++cib) {
        __syncthreads();            // previous compute done reading LDS
        WRITE_LDS();                // waits vmcnt on staged regs only
        if (cib < 15) LOAD_CIB(cib + 1);   // prefetch: in flight across compute
        __syncthreads();            // LDS writes visible

#pragma unroll
        for (int tap = 0; tap < 9; ++tap) {
            const int kh = tap / 3, kw = tap - kh * 3;
            const int r = wv + kh;
            short8 wf0 = *(const short8*)&ws[((tap * 2 + 0) * 64 + lane) * 8];
            short8 wf1 = *(const short8*)&ws[((tap * 2 + 1) * 64 + lane) * 8];
            short8 xf0 = *(const short8*)&xs[(((r * 2 + kh2) * 66) + kw + ln) * 8];
            short8 xf1 = *(const short8*)&xs[(((r * 2 + kh2) * 66) + kw + 32 + ln) * 8];
            acc00 = __builtin_amdgcn_mfma_f32_32x32x16_bf16(xf0, wf0, acc00, 0, 0, 0);
            acc01 = __builtin_amdgcn_mfma_f32_32x32x16_bf16(xf0, wf1, acc01, 0, 0, 0);
            acc10 = __builtin_amdgcn_mfma_f32_32x32x16_bf16(xf1, wf0, acc10, 0, 0, 0);
            acc11 = __builtin_amdgcn_mfma_f32_32x32x16_bf16(xf1, wf1, acc11, 0, 0, 0);
        }
    }
#undef LOAD_CIB
#undef WRITE_LDS

    // C/D: col(lane&31)=co, row=(reg&3)+8*(reg>>2)+4*kh2 = px within 32-tile
    const int h_out = h0 + wv;
    short* vt = value_t + ((size_t)(b * 4096 + h_out * 64)) * 256 + cot * 64;
#pragma unroll
    for (int reg = 0; reg < 16; ++reg) {
        int m = (reg & 3) + 8 * (reg >> 2) + 4 * kh2;
        vt[(size_t)m * 256 + ln]             = f2bf(acc00[reg]);
        vt[(size_t)m * 256 + 32 + ln]        = f2bf(acc01[reg]);
        vt[(size_t)(m + 32) * 256 + ln]      = f2bf(acc10[reg]);
        vt[(size_t)(m + 32) * 256 + 32 + ln] = f2bf(acc11[reg]);
    }
}

// ------------- bf16 NT-GEMM: C[M,N]fp32 = A[M,K] @ B[N,K]^T -----------------
// Fragments loaded directly from global (both operands K-contiguous).
// Block 128 thr = 2 waves; block tile 64m x 128n; wave: 32m x 4 n-tiles.
__global__ __launch_bounds__(128) void gemm_nt_bf16(const short* __restrict__ A,
                                                    const short* __restrict__ B,
                                                    float* __restrict__ C, int K,
                                                    long sA, long sB, long sC,
                                                    int ldc, int tilesN) {
    const int mt = blockIdx.x / tilesN, nt = blockIdx.x % tilesN;
    A += (size_t)blockIdx.y * sA;
    B += (size_t)blockIdx.y * sB;
    C += (size_t)blockIdx.y * sC;
    const int wv = threadIdx.x >> 6, l = threadIdx.x & 63;
    const int ln = l & 31, kh = l >> 5;
    const short* arow = A + (size_t)(mt * 64 + wv * 32 + ln) * K + kh * 8;
    const short* brow = B + (size_t)(nt * 128 + ln) * K + kh * 8;
    floatx16 acc0 = {}, acc1 = {}, acc2 = {}, acc3 = {};
#pragma unroll 2
    for (int k0 = 0; k0 < K; k0 += 16) {
        short8 a  = *(const short8*)&arow[k0];
        short8 b0 = *(const short8*)&brow[k0];
        short8 b1 = *(const short8*)&brow[(size_t)32 * K + k0];
        short8 b2 = *(const short8*)&brow[(size_t)64 * K + k0];
        short8 b3 = *(const short8*)&brow[(size_t)96 * K + k0];
        acc0 = __builtin_amdgcn_mfma_f32_32x32x16_bf16(a, b0, acc0, 0, 0, 0);
        acc1 = __builtin_amdgcn_mfma_f32_32x32x16_bf16(a, b1, acc1, 0, 0, 0);
        acc2 = __builtin_amdgcn_mfma_f32_32x32x16_bf16(a, b2, acc2, 0, 0, 0);
        acc3 = __builtin_amdgcn_mfma_f32_32x32x16_bf16(a, b3, acc3, 0, 0, 0);
    }
    const int n0 = nt * 128;
#pragma unroll
    for (int reg = 0; reg < 16; ++reg) {
        int m = mt * 64 + wv * 32 + (reg & 3) + 8 * (reg >> 2) + 4 * kh;
        float* crow = C + (size_t)m * ldc + n0 + ln;
        crow[0]  = acc0[reg];
        crow[32] = acc1[reg];
        crow[64] = acc2[reg];
        crow[96] = acc3[reg];
    }
}

// ------ final GEMM: out[256,4096] = attn2[256,256] @ value_t[4096,256]^T ----
// 512 thr = 8 waves; tile 256m(all) x 128n. Wave w: rows [32w,32w+32), all
// waves share the same 128 B rows per k-step (L1 broadcast) -> B read once.
__global__ __launch_bounds__(512) void gemm_bwide(const short* __restrict__ A,
                                                  const short* __restrict__ B,
                                                  float* __restrict__ C,
                                                  long sA, long sB, long sC) {
    const int nt = blockIdx.x;           // 32 n-tiles of 128
    A += (size_t)blockIdx.y * sA;
    B += (size_t)blockIdx.y * sB;
    C += (size_t)blockIdx.y * sC;
    const int wid = threadIdx.x >> 6, l = threadIdx.x & 63;
    const int ln = l & 31, kh = l >> 5;
    const short* arow = A + (size_t)(wid * 32 + ln) * 256 + kh * 8;
    const short* brow = B + (size_t)(nt * 128 + ln) * 256 + kh * 8;
    floatx16 acc0 = {}, acc1 = {}, acc2 = {}, acc3 = {};
#pragma unroll 2
    for (int k0 = 0; k0 < 256; k0 += 16) {
        short8 a  = *(const short8*)&arow[k0];
        short8 b0 = *(const short8*)&brow[k0];
        short8 b1 = *(const short8*)&brow[32 * 256 + k0];
        short8 b2 = *(const short8*)&brow[64 * 256 + k0];
        short8 b3 = *(const short8*)&brow[96 * 256 + k0];
        acc0 = __builtin_amdgcn_mfma_f32_32x32x16_bf16(a, b0, acc0, 0, 0, 0);
        acc1 = __builtin_amdgcn_mfma_f32_32x32x16_bf16(a, b1, acc1, 0, 0, 0);
        acc2 = __builtin_amdgcn_mfma_f32_32x32x16_bf16(a, b2, acc2, 0, 0, 0);
        acc3 = __builtin_amdgcn_mfma_f32_32x32x16_bf16(a, b3, acc3, 0, 0, 0);
    }
    const int n0 = nt * 128;
#pragma unroll
    for (int reg = 0; reg < 16; ++reg) {
        int m = wid * 32 + (reg & 3) + 8 * (reg >> 2) + 4 * kh;
        float* crow = C + (size_t)m * 4096 + n0 + ln;
        crow[0]  = acc0[reg];
        crow[32] = acc1[reg];
        crow[64] = acc2[reg];
        crow[96] = acc3[reg];
    }
}

// ---------------- fp32 GEMM 64x64 (kept for tiny attn2), opt bf16 out -------
template <int BT, int OB>
__global__ __launch_bounds__(256) void gemm64(const float* __restrict__ A,
                                              const float* __restrict__ B,
                                              float* __restrict__ C, int K,
                                              long sA, long sB, long sC,
                                              int ldA, int ldB, int ldC, int tilesN) {
    const int m0 = (blockIdx.x / tilesN) * 64;
    const int n0 = (blockIdx.x % tilesN) * 64;
    A += (size_t)blockIdx.y * sA;
    B += (size_t)blockIdx.y * sB;
    const size_t coff = (size_t)blockIdx.y * sC;
    __shared__ float As[16][68], Bs[16][68];
    const int tid = threadIdx.x;
    const int tx = tid & 15, ty = tid >> 4;
    const int mm = tid >> 2, kk4 = (tid & 3) * 4;
    float acc[4][4] = {};

    for (int k0 = 0; k0 < K; k0 += 16) {
        __syncthreads();
        {
            float4 a = *(const float4*)&A[(size_t)(m0 + mm) * ldA + k0 + kk4];
            As[kk4 + 0][mm] = a.x; As[kk4 + 1][mm] = a.y;
            As[kk4 + 2][mm] = a.z; As[kk4 + 3][mm] = a.w;
        }
        if (BT) {
            float4 bv = *(const float4*)&B[(size_t)(n0 + mm) * ldB + k0 + kk4];
            Bs[kk4 + 0][mm] = bv.x; Bs[kk4 + 1][mm] = bv.y;
            Bs[kk4 + 2][mm] = bv.z; Bs[kk4 + 3][mm] = bv.w;
        } else {
            int bk = tid >> 4, bn = (tid & 15) * 4;
            *(float4*)&Bs[bk][bn] = *(const float4*)&B[(size_t)(k0 + bk) * ldB + n0 + bn];
        }
        __syncthreads();
#pragma unroll
        for (int kk = 0; kk < 16; kk++) {
            float4 a = *(float4*)&As[kk][ty * 4];
            float4 bv = *(float4*)&Bs[kk][tx * 4];
            float av[4] = {a.x, a.y, a.z, a.w};
            float bb[4] = {bv.x, bv.y, bv.z, bv.w};
#pragma unroll
            for (int i = 0; i < 4; i++)
#pragma unroll
                for (int j = 0; j < 4; j++) acc[i][j] += av[i] * bb[j];
        }
    }
#pragma unroll
    for (int i = 0; i < 4; i++) {
        if (OB) {
            short* Cs = (short*)C + coff;
            short4 o;
            o.x = f2bf(acc[i][0]); o.y = f2bf(acc[i][1]);
            o.z = f2bf(acc[i][2]); o.w = f2bf(acc[i][3]);
            *(short4*)&Cs[(size_t)(m0 + ty * 4 + i) * ldC + n0 + tx * 4] = o;
        } else {
            float* Cf = (float*)C + coff;
            float4 o = make_float4(acc[i][0], acc[i][1], acc[i][2], acc[i][3]);
            *(float4*)&Cf[(size_t)(m0 + ty * 4 + i) * ldC + n0 + tx * 4] = o;
        }
    }
}

// ---------------- softmax over last dim (256) with scale + bias -------------
__global__ __launch_bounds__(256) void softmax_kernel(float* __restrict__ sim,
                                                      const float* __restrict__ rm) {
    int row  = blockIdx.x * 4 + (threadIdx.x >> 6);
    int lane = threadIdx.x & 63;
    int c = row & 255;
    float4 v = *(float4*)&sim[(size_t)row * 256 + lane * 4];
    const float4 bias = *(const float4*)&rm[c * 256 + lane * 4];
    v.x = v.x * 0.0625f + bias.x;
    v.y = v.y * 0.0625f + bias.y;
    v.z = v.z * 0.0625f + bias.z;
    v.w = v.w * 0.0625f + bias.w;
    float m = fmaxf(fmaxf(v.x, v.y), fmaxf(v.z, v.w));
#pragma unroll
    for (int off = 32; off > 0; off >>= 1) m = fmaxf(m, __shfl_xor(m, off, 64));
    float e0 = __expf(v.x - m), e1 = __expf(v.y - m);
    float e2 = __expf(v.z - m), e3 = __expf(v.w - m);
    float s = e0 + e1 + e2 + e3;
#pragma unroll
    for (int off = 32; off > 0; off >>= 1) s += __shfl_xor(s, off, 64);
    float inv = 1.f / s;
    float4 o = make_float4(e0 * inv, e1 * inv, e2 * inv, e3 * inv);
    *(float4*)&sim[(size_t)row * 256 + lane * 4] = o;
}

extern "C" void kernel_launch(void* const* d_in, const int* in_sizes, int n_in,
                              void* d_out, int out_size, void* d_ws, size_t ws_size,
                              hipStream_t stream) {
    const float* x     = (const float*)d_in[0];
    const float* x_mid = (const float*)d_in[1];
    const float* g_w   = (const float*)d_in[2];
    const float* w_w   = (const float*)d_in[3];
    const float* w1    = (const float*)d_in[4];
    const float* w2    = (const float*)d_in[5];
    float* out = (float*)d_out;

    char* ws = (char*)d_ws;
    short* value_t = (short*)ws;                                   // 67.1 MB [b][px][co]
    float* sim     = (float*)(ws + (size_t)NB * NPIX * NC * 2);    // 8.4 MB
    short* attn2_b = (short*)(sim + (size_t)NB * NC * NC);         // 4.2 MB [b][co][d]
    float* rm      = (float*)(attn2_b + (size_t)NB * NC * NC);     // 0.26 MB
    short* xt      = (short*)(rm + NC * NC);                       // 67.1 MB
    short* xb      = xt + (size_t)NB * NPIX * NC;                  // 67.1 MB
    short* wt      = xb + (size_t)NB * NC * NPIX;                  // 1.18 MB

    cvt_w_kernel<<<288, 256, 0, stream>>>(g_w, wt);
    cvt_x_kernel<<<dim3(64, 32), 256, 0, stream>>>(x_mid, xt);
    cvt_bf16_kernel<<<16384, 256, 0, stream>>>(x, xb);
    rm_kernel<<<256, 256, 0, stream>>>(w1, w2, rm);
    // value_t[b][px][co] = conv3x3(x_mid, g_w)
    conv_mfma<<<dim3(16, 4, 32), 256, 0, stream>>>(xt, wt, value_t);
    // sim = xb @ xb^T   (M=N=256, K=4096)
    gemm_nt_bf16<<<dim3(8, 32), 128, 0, stream>>>(
        xb, xb, sim, 4096,
        (long)NC * NPIX, (long)NC * NPIX, (long)NC * NC, NC, 2);
    softmax_kernel<<<2048, 256, 0, stream>>>(sim, rm);
    // attn2_b = bf16(w_w @ attn)  (M=N=K=256; A not batched)
    gemm64<0, 1><<<dim3(16, 32), 256, 0, stream>>>(
        w_w, sim, (float*)attn2_b, 256,
        0L, (long)NC * NC, (long)NC * NC,
        NC, NC, NC, 4);
    // out[b][co][px] = attn2_b @ value_t^T  (M=256, N=4096, K=256)
    gemm_bwide<<<dim3(32, 32), 512, 0, stream>>>(
        attn2_b, value_t, out,
        (long)NC * NC, (long)NPIX * NC, (long)NC * NPIX);
}